// Round 1
// baseline (1052.285 us; speedup 1.0000x reference)
//
#include <hip/hip_runtime.h>
#include <math.h>

// Problem constants (from reference):
//   x: [4096, 49152] f32, weight: [16384, 6] f32, out: [4096, 3] f32
static constexpr int NB   = 16384;        // number of 3x3 blocks
static constexpr int COLS = NB * 3;       // 49152
static constexpr int VEC  = COLS / 4;     // 12288 float4 per row
static constexpr int ROWS = 4096;
static constexpr int TPB  = 256;

__device__ __forceinline__ float softplus_f(float v) {
    // numerically stable softplus
    return log1pf(expf(-fabsf(v))) + fmaxf(v, 0.0f);
}

// Expand weight [NB,6] -> three SoA arrays Wj[COLS], Wj[3n+i] = W[n][j][i]
// where W = M^T M (symmetric):
//   M = [[a,b,c],[0,d,e],[0,0,f]], a=sp(w0),b=w1,c=w2,d=sp(w3),e=w4,f=sp(w5)
__global__ void build_wexp(const float* __restrict__ w,
                           float* __restrict__ W0,
                           float* __restrict__ W1,
                           float* __restrict__ W2) {
    int n = blockIdx.x * blockDim.x + threadIdx.x;
    if (n >= NB) return;
    float w0 = w[n * 6 + 0], w1 = w[n * 6 + 1], w2 = w[n * 6 + 2];
    float w3 = w[n * 6 + 3], w4 = w[n * 6 + 4], w5 = w[n * 6 + 5];
    float a = softplus_f(w0), b = w1, c = w2;
    float d = softplus_f(w3), e = w4, f = softplus_f(w5);
    float W00 = a * a;
    float W01 = a * b;
    float W02 = a * c;
    float W11 = b * b + d * d;
    float W12 = b * c + d * e;
    float W22 = c * c + e * e + f * f;
    int base = 3 * n;
    W0[base + 0] = W00; W0[base + 1] = W01; W0[base + 2] = W02;
    W1[base + 0] = W01; W1[base + 1] = W11; W1[base + 2] = W12;
    W2[base + 0] = W02; W2[base + 1] = W12; W2[base + 2] = W22;
}

// One block per row: out[row][j] = dot(x[row,:], Wj[:]).
// x stream is fully coalesced float4; weight re-reads are L2-served (576 KB).
__global__ __launch_bounds__(TPB) void row_reduce(
    const float4* __restrict__ x,
    const float4* __restrict__ W0,
    const float4* __restrict__ W1,
    const float4* __restrict__ W2,
    float* __restrict__ out) {
    const int row = blockIdx.x;
    const float4* __restrict__ xr = x + (size_t)row * VEC;

    float a0 = 0.f, a1 = 0.f, a2 = 0.f;
    #pragma unroll 4
    for (int v = threadIdx.x; v < VEC; v += TPB) {
        float4 xv = xr[v];
        float4 q0 = W0[v];
        float4 q1 = W1[v];
        float4 q2 = W2[v];
        a0 = fmaf(xv.x, q0.x, fmaf(xv.y, q0.y, fmaf(xv.z, q0.z, fmaf(xv.w, q0.w, a0))));
        a1 = fmaf(xv.x, q1.x, fmaf(xv.y, q1.y, fmaf(xv.z, q1.z, fmaf(xv.w, q1.w, a1))));
        a2 = fmaf(xv.x, q2.x, fmaf(xv.y, q2.y, fmaf(xv.z, q2.z, fmaf(xv.w, q2.w, a2))));
    }

    // wave-64 butterfly reduce
    #pragma unroll
    for (int off = 32; off > 0; off >>= 1) {
        a0 += __shfl_down(a0, off);
        a1 += __shfl_down(a1, off);
        a2 += __shfl_down(a2, off);
    }

    __shared__ float red[TPB / 64][3];
    const int lane = threadIdx.x & 63;
    const int wv   = threadIdx.x >> 6;
    if (lane == 0) {
        red[wv][0] = a0;
        red[wv][1] = a1;
        red[wv][2] = a2;
    }
    __syncthreads();
    if (threadIdx.x == 0) {
        float s0 = 0.f, s1 = 0.f, s2 = 0.f;
        #pragma unroll
        for (int i = 0; i < TPB / 64; ++i) {
            s0 += red[i][0];
            s1 += red[i][1];
            s2 += red[i][2];
        }
        out[row * 3 + 0] = s0;
        out[row * 3 + 1] = s1;
        out[row * 3 + 2] = s2;
    }
}

extern "C" void kernel_launch(void* const* d_in, const int* in_sizes, int n_in,
                              void* d_out, int out_size, void* d_ws, size_t ws_size,
                              hipStream_t stream) {
    const float* x = (const float*)d_in[0];
    const float* w = (const float*)d_in[1];
    float* out = (float*)d_out;

    // workspace: 3 * COLS floats = 576 KB of expanded weights
    float* W0 = (float*)d_ws;
    float* W1 = W0 + COLS;
    float* W2 = W1 + COLS;

    build_wexp<<<(NB + TPB - 1) / TPB, TPB, 0, stream>>>(w, W0, W1, W2);
    row_reduce<<<ROWS, TPB, 0, stream>>>(
        (const float4*)x, (const float4*)W0, (const float4*)W1,
        (const float4*)W2, out);
}